// Round 1
// 273.304 us; speedup vs baseline: 1.0010x; 1.0010x over previous
//
#include <hip/hip_runtime.h>
#include <hip/hip_fp16.h>

#define N_NODES 100000
#define PAD_N   100096                   // 782 * 128, padded M for GEMM tiles
#define IN_DIM 128
#define HID 128
#define N_REL 2
#define N_EDGES 500000
#define M_SEG (N_REL * N_NODES)          // 200000 (rel,node) segments
#define SCAN_BLK 1024
#define SCAN_NB ((M_SEG + SCAN_BLK - 1) / SCAN_BLK)   // 196

#define CVT_BLOCKS 12500                 // N_NODES*IN_DIM/4 / 256
#define PACK_BLOCKS 48                   // 2*12*8*64 / 256
#define HIST_BLOCKS 1954                 // ceil(N_EDGES/256)

typedef __attribute__((ext_vector_type(8))) _Float16 half8;
typedef __attribute__((ext_vector_type(4))) float float4v;

__device__ __forceinline__ unsigned short f2h(float f) {
    return __half_as_ushort(__float2half(f));   // RNE
}

// ---------------------------------------------------------------------------
// Fused prep: cvt (x fp32->fp16) | pack (weights->B-frag order, fp16) | hist.
// ---------------------------------------------------------------------------
__global__ __launch_bounds__(256) void prep_kernel(
    const float* __restrict__ X, unsigned short* __restrict__ Xb,
    const float* __restrict__ Wroot1, const float* __restrict__ Wrel1,
    const float* __restrict__ Wroot2, const float* __restrict__ Wrel2,
    unsigned short* __restrict__ Wp,
    const int* __restrict__ ei, const int* __restrict__ et,
    unsigned* __restrict__ cnt)
{
    int bid = blockIdx.x;
    if (bid < CVT_BLOCKS) {
        int i = bid * 256 + threadIdx.x;
        if (i >= N_NODES * IN_DIM / 4) return;
        float4 v = ((const float4*)X)[i];
        ushort4 o;
        o.x = f2h(v.x); o.y = f2h(v.y); o.z = f2h(v.z); o.w = f2h(v.w);
        ((ushort4*)Xb)[i] = o;
    } else if (bid < CVT_BLOCKS + PACK_BLOCKS) {
        int tid = (bid - CVT_BLOCKS) * 256 + threadIdx.x;
        int layer = tid / 6144;
        int rem   = tid % 6144;
        int ks    = rem / 512;
        int rem2  = rem % 512;
        int nt    = rem2 / 64;
        int lane  = rem2 % 64;
        int seg = ks >> 2;
        int kl  = (ks & 3) * 32 + (lane >> 4) * 8;
        int chan = nt * 16 + (lane & 15);
        const float* Wroot = layer ? Wroot2 : Wroot1;
        const float* Wrel  = layer ? Wrel2  : Wrel1;
        const float* W = (seg == 0) ? Wroot : (Wrel + (size_t)(seg - 1) * 128 * 128);
        unsigned short* dst = Wp + (size_t)tid * 8;
        #pragma unroll
        for (int j = 0; j < 8; ++j)
            dst[j] = f2h(W[(size_t)(kl + j) * 128 + chan]);
    } else {
        int e = (bid - CVT_BLOCKS - PACK_BLOCKS) * 256 + threadIdx.x;
        if (e >= N_EDGES) return;
        int dst = ei[N_EDGES + e];
        int r = et[e];
        atomicAdd(cnt + (size_t)r * N_NODES + dst, 1u);
    }
}

// ---------------------------------------------------------------------------
// Scan chain for CSR row starts
// ---------------------------------------------------------------------------
__global__ __launch_bounds__(256) void scan1_kernel(
    const unsigned* __restrict__ cnt,
    unsigned* __restrict__ rs, unsigned* __restrict__ bsums)
{
    __shared__ unsigned sdata[256];
    int t = threadIdx.x;
    int base = blockIdx.x * SCAN_BLK + t * 4;
    unsigned v[4]; unsigned s = 0;
    #pragma unroll
    for (int j = 0; j < 4; ++j) {
        v[j] = (base + j < M_SEG) ? cnt[base + j] : 0u;
        s += v[j];
    }
    sdata[t] = s;
    __syncthreads();
    #pragma unroll
    for (int off = 1; off < 256; off <<= 1) {
        unsigned x = (t >= off) ? sdata[t - off] : 0u;
        __syncthreads();
        if (t >= off) sdata[t] += x;
        __syncthreads();
    }
    unsigned excl = (t > 0) ? sdata[t - 1] : 0u;
    if (t == 255) bsums[blockIdx.x] = sdata[255];
    unsigned run = excl;
    #pragma unroll
    for (int j = 0; j < 4; ++j) {
        if (base + j < M_SEG) rs[base + j] = run;
        run += v[j];
    }
}

__global__ __launch_bounds__(256) void scan2_kernel(unsigned* __restrict__ bsums)
{
    __shared__ unsigned sdata[256];
    int t = threadIdx.x;
    sdata[t] = (t < SCAN_NB) ? bsums[t] : 0u;
    __syncthreads();
    #pragma unroll
    for (int off = 1; off < 256; off <<= 1) {
        unsigned x = (t >= off) ? sdata[t - off] : 0u;
        __syncthreads();
        if (t >= off) sdata[t] += x;
        __syncthreads();
    }
    if (t < SCAN_NB) bsums[t] = (t > 0) ? sdata[t - 1] : 0u;
}

__global__ __launch_bounds__(256) void scan3_kernel(
    unsigned* __restrict__ rs, const unsigned* __restrict__ bsums,
    unsigned* __restrict__ cursor)
{
    int i = blockIdx.x * blockDim.x + threadIdx.x;
    if (i < M_SEG) {
        unsigned v = rs[i] + bsums[i >> 10];
        rs[i] = v;
        cursor[i] = v;
    }
    if (i == 0) rs[M_SEG] = N_EDGES;
}

__global__ __launch_bounds__(256) void fill_kernel(
    const int* __restrict__ ei, const int* __restrict__ et,
    unsigned* __restrict__ cursor, unsigned* __restrict__ csr)
{
    int e = blockIdx.x * blockDim.x + threadIdx.x;
    if (e >= N_EDGES) return;
    int src = ei[e];
    int dst = ei[N_EDGES + e];
    int r = et[e];
    unsigned pos = atomicAdd(cursor + (size_t)r * N_NODES + dst, 1u);
    csr[pos] = (unsigned)src;
}

// ---------------------------------------------------------------------------
// Fused gather + MFMA GEMM (fp16).
//
// The relation-mean A-fragments for MFMA segs 1-2 have per-lane layout
//   mean_r[rowbase + mt*16 + l15][ksl*32 + quad*8 .. +7]
// i.e. each lane owns a private 16B slice of each mean row.  So each lane
// computes its own mean fragments in registers by walking the CSR list of
// its (r, node) segment (avg degree 2.5) with packed v_pk_add_f16, then
// scaling by 1/cnt.  This removes the agg buffer entirely: no 51.2 MB
// write + 51.2 MB read per layer, no separate gather kernel, and the
// random gathered reads overlap the async B staging (global_load_lds
// issued before the gather phase).
// ---------------------------------------------------------------------------
template <bool FINAL>
__global__ __launch_bounds__(256) void gemm_kernel(
    const unsigned short* __restrict__ Xin,   // [PAD_N][128] fp16 (layer input + gather source)
    const unsigned* __restrict__ rs,          // [M_SEG+1] CSR row starts
    const unsigned* __restrict__ csr,         // [N_EDGES] src node per slot
    const unsigned short* __restrict__ Wp,    // packed [12][8][64][8] fp16
    const float* __restrict__ bias,           // [128] fp32
    unsigned short* __restrict__ Hout,        // [PAD_N][128] fp16 (!FINAL)
    const float* __restrict__ Wc,             // [128][2] fp32 (FINAL)
    const float* __restrict__ bc,             // [2] fp32 (FINAL)
    float* __restrict__ Out)                  // [N][2] fp32 (FINAL)
{
    __shared__ unsigned short ldsB[2][3 * 8 * 512];   // 2 x 24 KB

    const int t    = threadIdx.x;
    const int w    = t >> 6;          // wave 0..3
    const int lane = t & 63;
    const int l15  = lane & 15;
    const int quad = lane >> 4;
    const int rowbase = blockIdx.x * 128 + w * 32;   // this wave's 32 nodes
    const int koff = quad * 8;

    // stage the 24 frags of phase ph into buffer buf (6 per wave)
    auto stage = [&](int ph, int buf) {
        #pragma unroll
        for (int fi = 0; fi < 6; ++fi) {
            int f  = fi * 4 + w;          // 0..23
            int sl = f >> 3;              // phase-local K-step 0..2
            int nt = f & 7;
            int ks = ph * 3 + sl;
            const unsigned short* g = Wp + ((size_t)(ks * 8 + nt) * 64 + lane) * 8;
            unsigned short* l = &ldsB[buf][(size_t)(sl * 8 + nt) * 512];  // wave-uniform
            __builtin_amdgcn_global_load_lds(
                (const __attribute__((address_space(1))) unsigned int*)g,
                (__attribute__((address_space(3))) unsigned int*)l, 16, 0, 0);
        }
    };

    stage(0, 0);                      // B phase-0 in flight during gather

    const uint4* __restrict__ X4 = (const uint4*)Xin;   // 16B units

    // ---- seg-0 A-frags (this lane's own rows, sequential loads) ----
    half8 ax[2][4];                   // [mt][ksl]
    #pragma unroll
    for (int mt = 0; mt < 2; ++mt)
        #pragma unroll
        for (int ksl = 0; ksl < 4; ++ksl)
            ax[mt][ksl] = *(const half8*)(Xin +
                (size_t)(rowbase + mt * 16 + l15) * 128 + ksl * 32 + koff);

    // ---- in-register gather: mean frags for segs 1-2 ----
    half8 ag[2][2][4];                // [r][mt][ksl]
    #pragma unroll
    for (int r = 0; r < 2; ++r) {
        #pragma unroll
        for (int mt = 0; mt < 2; ++mt) {
            int node = rowbase + mt * 16 + l15;
            unsigned start = 0, end = 0;
            if (node < N_NODES) {
                unsigned sg = (unsigned)r * N_NODES + (unsigned)node;
                start = rs[sg];
                end   = rs[sg + 1];
            }
            __half2 a2[4][4];
            #pragma unroll
            for (int ksl = 0; ksl < 4; ++ksl)
                #pragma unroll
                for (int j = 0; j < 4; ++j)
                    a2[ksl][j] = __float2half2_rn(0.f);

            for (unsigned p = start; p < end; ++p) {
                unsigned s = csr[p];
                const uint4* row = X4 + ((size_t)s << 4) + quad;
                uint4 v0 = row[0];      // ksl 0: ch quad*8..+7
                uint4 v1 = row[4];      // ksl 1: +32
                uint4 v2 = row[8];      // ksl 2: +64
                uint4 v3 = row[12];     // ksl 3: +96
                a2[0][0] = __hadd2(a2[0][0], *(const __half2*)&v0.x);
                a2[0][1] = __hadd2(a2[0][1], *(const __half2*)&v0.y);
                a2[0][2] = __hadd2(a2[0][2], *(const __half2*)&v0.z);
                a2[0][3] = __hadd2(a2[0][3], *(const __half2*)&v0.w);
                a2[1][0] = __hadd2(a2[1][0], *(const __half2*)&v1.x);
                a2[1][1] = __hadd2(a2[1][1], *(const __half2*)&v1.y);
                a2[1][2] = __hadd2(a2[1][2], *(const __half2*)&v1.z);
                a2[1][3] = __hadd2(a2[1][3], *(const __half2*)&v1.w);
                a2[2][0] = __hadd2(a2[2][0], *(const __half2*)&v2.x);
                a2[2][1] = __hadd2(a2[2][1], *(const __half2*)&v2.y);
                a2[2][2] = __hadd2(a2[2][2], *(const __half2*)&v2.z);
                a2[2][3] = __hadd2(a2[2][3], *(const __half2*)&v2.w);
                a2[3][0] = __hadd2(a2[3][0], *(const __half2*)&v3.x);
                a2[3][1] = __hadd2(a2[3][1], *(const __half2*)&v3.y);
                a2[3][2] = __hadd2(a2[3][2], *(const __half2*)&v3.z);
                a2[3][3] = __hadd2(a2[3][3], *(const __half2*)&v3.w);
            }

            unsigned c = end - start;
            float scf = 1.0f / (float)(c > 0u ? c : 1u);
            __half2 s2 = __float2half2_rn(scf);
            #pragma unroll
            for (int ksl = 0; ksl < 4; ++ksl) {
                half8 h;
                #pragma unroll
                for (int j = 0; j < 4; ++j)
                    ((__half2*)&h)[j] = __hmul2(a2[ksl][j], s2);
                ag[r][mt][ksl] = h;
            }
        }
    }

    // A-frag select (ks, mt compile-time after unroll)
    auto af = [&](int ks, int mt) -> half8 {
        return (ks < 4) ? ax[mt][ks & 3] : ag[(ks >> 2) - 1][mt][ks & 3];
    };

    float4v acc[2][8];
    #pragma unroll
    for (int nt = 0; nt < 8; ++nt) {
        float bv = bias[nt * 16 + l15];
        #pragma unroll
        for (int mt = 0; mt < 2; ++mt)
            acc[mt][nt] = float4v{bv, bv, bv, bv};
    }

    __syncthreads();                      // phase-0 B staged (vmcnt drained)

    #pragma unroll
    for (int ph = 0; ph < 4; ++ph) {
        if (ph < 3) stage(ph + 1, (ph + 1) & 1);   // overlap staging with compute
        #pragma unroll
        for (int sl = 0; sl < 3; ++sl) {
            int ks = ph * 3 + sl;
            half8 b[8];
            #pragma unroll
            for (int nt = 0; nt < 8; ++nt)
                b[nt] = *(const half8*)(&ldsB[ph & 1][(size_t)(sl * 8 + nt) * 512] + lane * 8);
            #pragma unroll
            for (int nt = 0; nt < 8; ++nt) {
                acc[0][nt] = __builtin_amdgcn_mfma_f32_16x16x32_f16(af(ks, 0), b[nt], acc[0][nt], 0, 0, 0);
                acc[1][nt] = __builtin_amdgcn_mfma_f32_16x16x32_f16(af(ks, 1), b[nt], acc[1][nt], 0, 0, 0);
            }
        }
        __syncthreads();   // readers done with buf(ph&1); stage(ph+1) drained
    }

    if (!FINAL) {
        // D layout: row = quad*4 + r, col = l15 (within each 16x16 tile)
        #pragma unroll
        for (int mt = 0; mt < 2; ++mt) {
            #pragma unroll
            for (int r = 0; r < 4; ++r) {
                int node = rowbase + mt * 16 + quad * 4 + r;
                unsigned short* hp = Hout + (size_t)node * 128 + l15;
                #pragma unroll
                for (int nt = 0; nt < 8; ++nt)
                    hp[nt * 16] = f2h(fmaxf(acc[mt][nt][r], 0.f));
            }
        }
    } else {
        float wc0[8], wc1[8];
        #pragma unroll
        for (int nt = 0; nt < 8; ++nt) {
            wc0[nt] = Wc[(nt * 16 + l15) * 2 + 0];
            wc1[nt] = Wc[(nt * 16 + l15) * 2 + 1];
        }
        float b0 = bc[0], b1 = bc[1];
        #pragma unroll
        for (int mt = 0; mt < 2; ++mt) {
            #pragma unroll
            for (int r = 0; r < 4; ++r) {
                float l0 = 0.f, l1 = 0.f;
                #pragma unroll
                for (int nt = 0; nt < 8; ++nt) {
                    float h = fmaxf(acc[mt][nt][r], 0.f);
                    l0 += h * wc0[nt];
                    l1 += h * wc1[nt];
                }
                #pragma unroll
                for (int off = 8; off > 0; off >>= 1) {
                    l0 += __shfl_down(l0, off, 16);
                    l1 += __shfl_down(l1, off, 16);
                }
                int node = rowbase + mt * 16 + quad * 4 + r;
                if (l15 == 0 && node < N_NODES) {
                    Out[(size_t)node * 2 + 0] = l0 + b0;
                    Out[(size_t)node * 2 + 1] = l1 + b1;
                }
            }
        }
    }
}

extern "C" void kernel_launch(void* const* d_in, const int* in_sizes, int n_in,
                              void* d_out, int out_size, void* d_ws, size_t ws_size,
                              hipStream_t stream)
{
    const float* x      = (const float*)d_in[0];
    const int*   ei     = (const int*)d_in[1];
    const int*   et     = (const int*)d_in[2];
    const float* Wrel1  = (const float*)d_in[3];
    const float* Wroot1 = (const float*)d_in[4];
    const float* b1     = (const float*)d_in[5];
    const float* Wrel2  = (const float*)d_in[6];
    const float* Wroot2 = (const float*)d_in[7];
    const float* b2     = (const float*)d_in[8];
    const float* Wc     = (const float*)d_in[9];
    const float* bc     = (const float*)d_in[10];
    float* out = (float*)d_out;

    char* ws = (char*)d_ws;
    size_t off = 0;
    auto alloc = [&](size_t bytes) {
        void* p = ws + off;
        off += (bytes + 255) & ~(size_t)255;
        return p;
    };
    unsigned short* xb    = (unsigned short*)alloc((size_t)PAD_N * IN_DIM * 2);
    unsigned short* h1b   = (unsigned short*)alloc((size_t)PAD_N * HID * 2);
    unsigned short* Wp    = (unsigned short*)alloc((size_t)2 * 12 * 8 * 64 * 8 * 2);
    unsigned*       rs    = (unsigned*)alloc((size_t)(M_SEG + 1) * 4);
    unsigned*       cursor= (unsigned*)alloc((size_t)M_SEG * 4);
    unsigned*       bsums = (unsigned*)alloc(256 * 4);
    unsigned*       csr   = (unsigned*)alloc((size_t)N_EDGES * 4);

    const int edge_blocks = (N_EDGES + 255) / 256;
    const int seg_blocks  = (M_SEG + 255) / 256;
    const int gemm_blocks = PAD_N / 128;                // 782
    const int prep_blocks = CVT_BLOCKS + PACK_BLOCKS + HIST_BLOCKS;

    // ---- CSR build + conversions (graph identical for both layers) ----
    hipMemsetAsync(cursor, 0, (size_t)M_SEG * 4, stream);
    prep_kernel<<<prep_blocks, 256, 0, stream>>>(
        x, xb, Wroot1, Wrel1, Wroot2, Wrel2, Wp, ei, et, cursor);
    scan1_kernel<<<SCAN_NB, 256, 0, stream>>>(cursor, rs, bsums);
    scan2_kernel<<<1, 256, 0, stream>>>(bsums);
    scan3_kernel<<<seg_blocks, 256, 0, stream>>>(rs, bsums, cursor);
    fill_kernel<<<edge_blocks, 256, 0, stream>>>(ei, et, cursor, csr);

    // ---- layer 1 (fused gather+gemm) ----
    gemm_kernel<false><<<gemm_blocks, 256, 0, stream>>>(
        xb, rs, csr, Wp, b1, h1b, nullptr, nullptr, nullptr);

    // ---- layer 2 (fused gather+gemm, FINAL classifier) ----
    gemm_kernel<true><<<gemm_blocks, 256, 0, stream>>>(
        h1b, rs, csr, Wp + (size_t)12 * 8 * 64 * 8, b2, nullptr, Wc, bc, out);
}

// Round 2
// 271.276 us; speedup vs baseline: 1.0085x; 1.0075x over previous
//
#include <hip/hip_runtime.h>
#include <hip/hip_fp16.h>

#define N_NODES 100000
#define PAD_N   100096                   // 782 * 128, padded M for GEMM tiles
#define IN_DIM 128
#define HID 128
#define N_REL 2
#define N_EDGES 500000
#define M_SEG (N_REL * N_NODES)          // 200000 (rel,node) segments
#define SCAN_BLK 1024
#define SCAN_NB ((M_SEG + SCAN_BLK - 1) / SCAN_BLK)   // 196

#define CVT_BLOCKS 12500                 // N_NODES*IN_DIM/4 / 256
#define PACK_BLOCKS 48                   // 2*12*8*64 / 256
#define HIST_BLOCKS 1954                 // ceil(N_EDGES/256)

typedef __attribute__((ext_vector_type(8))) _Float16 half8;
typedef __attribute__((ext_vector_type(4))) float float4v;

__device__ __forceinline__ unsigned short f2h(float f) {
    return __half_as_ushort(__float2half(f));   // RNE
}

// ---------------------------------------------------------------------------
// Fused prep: cvt (x fp32->fp16) | pack (weights->B-frag order, fp16) | hist.
// ---------------------------------------------------------------------------
__global__ __launch_bounds__(256) void prep_kernel(
    const float* __restrict__ X, unsigned short* __restrict__ Xb,
    const float* __restrict__ Wroot1, const float* __restrict__ Wrel1,
    const float* __restrict__ Wroot2, const float* __restrict__ Wrel2,
    unsigned short* __restrict__ Wp,
    const int* __restrict__ ei, const int* __restrict__ et,
    unsigned* __restrict__ cnt)
{
    int bid = blockIdx.x;
    if (bid < CVT_BLOCKS) {
        int i = bid * 256 + threadIdx.x;
        if (i >= N_NODES * IN_DIM / 4) return;
        float4 v = ((const float4*)X)[i];
        ushort4 o;
        o.x = f2h(v.x); o.y = f2h(v.y); o.z = f2h(v.z); o.w = f2h(v.w);
        ((ushort4*)Xb)[i] = o;
    } else if (bid < CVT_BLOCKS + PACK_BLOCKS) {
        int tid = (bid - CVT_BLOCKS) * 256 + threadIdx.x;
        int layer = tid / 6144;
        int rem   = tid % 6144;
        int ks    = rem / 512;
        int rem2  = rem % 512;
        int nt    = rem2 / 64;
        int lane  = rem2 % 64;
        int seg = ks >> 2;
        int kl  = (ks & 3) * 32 + (lane >> 4) * 8;
        int chan = nt * 16 + (lane & 15);
        const float* Wroot = layer ? Wroot2 : Wroot1;
        const float* Wrel  = layer ? Wrel2  : Wrel1;
        const float* W = (seg == 0) ? Wroot : (Wrel + (size_t)(seg - 1) * 128 * 128);
        unsigned short* dst = Wp + (size_t)tid * 8;
        #pragma unroll
        for (int j = 0; j < 8; ++j)
            dst[j] = f2h(W[(size_t)(kl + j) * 128 + chan]);
    } else {
        int e = (bid - CVT_BLOCKS - PACK_BLOCKS) * 256 + threadIdx.x;
        if (e >= N_EDGES) return;
        int dst = ei[N_EDGES + e];
        int r = et[e];
        atomicAdd(cnt + (size_t)r * N_NODES + dst, 1u);
    }
}

// ---------------------------------------------------------------------------
// Scan chain for CSR row starts
// ---------------------------------------------------------------------------
__global__ __launch_bounds__(256) void scan1_kernel(
    const unsigned* __restrict__ cnt,
    unsigned* __restrict__ rs, unsigned* __restrict__ bsums)
{
    __shared__ unsigned sdata[256];
    int t = threadIdx.x;
    int base = blockIdx.x * SCAN_BLK + t * 4;
    unsigned v[4]; unsigned s = 0;
    #pragma unroll
    for (int j = 0; j < 4; ++j) {
        v[j] = (base + j < M_SEG) ? cnt[base + j] : 0u;
        s += v[j];
    }
    sdata[t] = s;
    __syncthreads();
    #pragma unroll
    for (int off = 1; off < 256; off <<= 1) {
        unsigned x = (t >= off) ? sdata[t - off] : 0u;
        __syncthreads();
        if (t >= off) sdata[t] += x;
        __syncthreads();
    }
    unsigned excl = (t > 0) ? sdata[t - 1] : 0u;
    if (t == 255) bsums[blockIdx.x] = sdata[255];
    unsigned run = excl;
    #pragma unroll
    for (int j = 0; j < 4; ++j) {
        if (base + j < M_SEG) rs[base + j] = run;
        run += v[j];
    }
}

__global__ __launch_bounds__(256) void scan2_kernel(unsigned* __restrict__ bsums)
{
    __shared__ unsigned sdata[256];
    int t = threadIdx.x;
    sdata[t] = (t < SCAN_NB) ? bsums[t] : 0u;
    __syncthreads();
    #pragma unroll
    for (int off = 1; off < 256; off <<= 1) {
        unsigned x = (t >= off) ? sdata[t - off] : 0u;
        __syncthreads();
        if (t >= off) sdata[t] += x;
        __syncthreads();
    }
    if (t < SCAN_NB) bsums[t] = (t > 0) ? sdata[t - 1] : 0u;
}

__global__ __launch_bounds__(256) void scan3_kernel(
    unsigned* __restrict__ rs, const unsigned* __restrict__ bsums,
    unsigned* __restrict__ cursor)
{
    int i = blockIdx.x * blockDim.x + threadIdx.x;
    if (i < M_SEG) {
        unsigned v = rs[i] + bsums[i >> 10];
        rs[i] = v;
        cursor[i] = v;
    }
    if (i == 0) rs[M_SEG] = N_EDGES;
}

__global__ __launch_bounds__(256) void fill_kernel(
    const int* __restrict__ ei, const int* __restrict__ et,
    unsigned* __restrict__ cursor, unsigned* __restrict__ csr)
{
    int e = blockIdx.x * blockDim.x + threadIdx.x;
    if (e >= N_EDGES) return;
    int src = ei[e];
    int dst = ei[N_EDGES + e];
    int r = et[e];
    unsigned pos = atomicAdd(cursor + (size_t)r * N_NODES + dst, 1u);
    csr[pos] = (unsigned)src;
}

// ---------------------------------------------------------------------------
// Fused gather + MFMA GEMM (fp16), latency-optimized:
//  * the 4 (r,mt) CSR segment walks are INTERLEAVED in one loop: per
//    iteration 4 independent csr loads then 16 independent 16B row loads
//    are in flight (256 B MLP/lane); accumulation is predicated
//    v_pk_fma_f16.  Serial depth = max segment degree, not the sum.
//  * NO LDS, NO __syncthreads: B (96 KB, shared by all blocks, L2-resident)
//    is read per-wave straight from global with a depth-2 register
//    ping-pong prefetch (all indices compile-time under full unroll).
//    Waves are fully decoupled -> no waiting on the slowest gather wave.
// ---------------------------------------------------------------------------
template <bool FINAL>
__global__ __launch_bounds__(256) void gemm_kernel(
    const unsigned short* __restrict__ Xin,   // [PAD_N][128] fp16 (layer input + gather source)
    const unsigned* __restrict__ rs,          // [M_SEG+1] CSR row starts
    const unsigned* __restrict__ csr,         // [N_EDGES] src node per slot
    const unsigned short* __restrict__ Wp,    // packed [12][8][64][8] fp16
    const float* __restrict__ bias,           // [128] fp32
    unsigned short* __restrict__ Hout,        // [PAD_N][128] fp16 (!FINAL)
    const float* __restrict__ Wc,             // [128][2] fp32 (FINAL)
    const float* __restrict__ bc,             // [2] fp32 (FINAL)
    float* __restrict__ Out)                  // [N][2] fp32 (FINAL)
{
    const int t    = threadIdx.x;
    const int w    = t >> 6;          // wave 0..3
    const int lane = t & 63;
    const int l15  = lane & 15;
    const int quad = lane >> 4;
    const int rowbase = blockIdx.x * 128 + w * 32;   // this wave's 32 nodes
    const int koff = quad * 8;

    const uint4* __restrict__ X4 = (const uint4*)Xin;   // 16B units

    // ---- interleaved in-register gather: mean frags for segs 1-2 ----
    // walk index c = r*2 + mt
    unsigned p_[4], e_[4]; float inv_[4];
    #pragma unroll
    for (int r = 0; r < 2; ++r) {
        #pragma unroll
        for (int mt = 0; mt < 2; ++mt) {
            int c = r * 2 + mt;
            int node = rowbase + mt * 16 + l15;
            unsigned st = 0, en = 0;
            if (node < N_NODES) {
                unsigned sg = (unsigned)r * N_NODES + (unsigned)node;
                st = rs[sg];
                en = rs[sg + 1];
            }
            p_[c] = st; e_[c] = en;
            unsigned cdeg = en - st;
            inv_[c] = 1.0f / (float)(cdeg > 0u ? cdeg : 1u);
        }
    }

    __half2 a2[4][4][4];              // [c][ksl][j] — all statically indexed
    #pragma unroll
    for (int c = 0; c < 4; ++c)
        #pragma unroll
        for (int ksl = 0; ksl < 4; ++ksl)
            #pragma unroll
            for (int j = 0; j < 4; ++j)
                a2[c][ksl][j] = __float2half2_rn(0.f);

    const __half2 one2  = __float2half2_rn(1.f);
    const __half2 zero2 = __float2half2_rn(0.f);

    while (true) {
        bool act[4];
        bool anyl = false;
        #pragma unroll
        for (int c = 0; c < 4; ++c) { act[c] = p_[c] < e_[c]; anyl |= act[c]; }
        if (!__any(anyl)) break;

        // 4 independent csr loads
        unsigned s_[4];
        #pragma unroll
        for (int c = 0; c < 4; ++c)
            s_[c] = csr[act[c] ? p_[c] : 0u];

        // 16 independent 16B row loads (4 per walk, imm-offset siblings)
        uint4 v_[4][4];
        #pragma unroll
        for (int c = 0; c < 4; ++c) {
            const uint4* row = X4 + ((size_t)(act[c] ? s_[c] : 0u) << 4) + quad;
            v_[c][0] = row[0];
            v_[c][1] = row[4];
            v_[c][2] = row[8];
            v_[c][3] = row[12];
        }

        // predicated packed-fma accumulate
        #pragma unroll
        for (int c = 0; c < 4; ++c) {
            __half2 m = act[c] ? one2 : zero2;
            #pragma unroll
            for (int ksl = 0; ksl < 4; ++ksl)
                #pragma unroll
                for (int j = 0; j < 4; ++j)
                    a2[c][ksl][j] = __hfma2(((const __half2*)&v_[c][ksl])[j], m,
                                            a2[c][ksl][j]);
            p_[c] += act[c] ? 1u : 0u;
        }
    }

    // scale to means
    half8 ag[2][2][4];                // [r][mt][ksl]
    #pragma unroll
    for (int r = 0; r < 2; ++r)
        #pragma unroll
        for (int mt = 0; mt < 2; ++mt) {
            int c = r * 2 + mt;
            __half2 s2 = __float2half2_rn(inv_[c]);
            #pragma unroll
            for (int ksl = 0; ksl < 4; ++ksl) {
                half8 h;
                #pragma unroll
                for (int j = 0; j < 4; ++j)
                    ((__half2*)&h)[j] = __hmul2(a2[c][ksl][j], s2);
                ag[r][mt][ksl] = h;
            }
        }

    // ---- MFMA phase: B (and seg-0 A) direct-from-global, depth-2 prefetch ----
    auto ldB = [&](int ks, int nt) -> half8 {
        return *(const half8*)(Wp + ((size_t)(ks * 8 + nt) * 64 + lane) * 8);
    };
    const unsigned short* aBase0 = Xin + (size_t)(rowbase + l15) * 128 + koff;
    const unsigned short* aBase1 = aBase0 + 16 * 128;
    auto ldA = [&](int ks, int mt) -> half8 {
        return *(const half8*)((mt ? aBase1 : aBase0) + (ks & 3) * 32);
    };

    float4v acc[2][8];
    #pragma unroll
    for (int nt = 0; nt < 8; ++nt) {
        float bv = bias[nt * 16 + l15];
        #pragma unroll
        for (int mt = 0; mt < 2; ++mt)
            acc[mt][nt] = float4v{bv, bv, bv, bv};
    }

    half8 bb[2][8];                   // ping-pong, ks&1 is compile-time
    half8 aa[2][2];
    #pragma unroll
    for (int nt = 0; nt < 8; ++nt) bb[0][nt] = ldB(0, nt);
    aa[0][0] = ldA(0, 0);
    aa[0][1] = ldA(0, 1);

    #pragma unroll
    for (int ks = 0; ks < 12; ++ks) {
        if (ks + 1 < 12) {
            #pragma unroll
            for (int nt = 0; nt < 8; ++nt)
                bb[(ks + 1) & 1][nt] = ldB(ks + 1, nt);
            if (ks + 1 < 4) {
                aa[(ks + 1) & 1][0] = ldA(ks + 1, 0);
                aa[(ks + 1) & 1][1] = ldA(ks + 1, 1);
            }
        }
        half8 A0 = (ks < 4) ? aa[ks & 1][0] : ag[(ks >> 2) - 1][0][ks & 3];
        half8 A1 = (ks < 4) ? aa[ks & 1][1] : ag[(ks >> 2) - 1][1][ks & 3];
        #pragma unroll
        for (int nt = 0; nt < 8; ++nt) {
            acc[0][nt] = __builtin_amdgcn_mfma_f32_16x16x32_f16(A0, bb[ks & 1][nt], acc[0][nt], 0, 0, 0);
            acc[1][nt] = __builtin_amdgcn_mfma_f32_16x16x32_f16(A1, bb[ks & 1][nt], acc[1][nt], 0, 0, 0);
        }
    }

    if (!FINAL) {
        // D layout: row = quad*4 + r, col = l15 (within each 16x16 tile)
        #pragma unroll
        for (int mt = 0; mt < 2; ++mt) {
            #pragma unroll
            for (int r = 0; r < 4; ++r) {
                int node = rowbase + mt * 16 + quad * 4 + r;
                unsigned short* hp = Hout + (size_t)node * 128 + l15;
                #pragma unroll
                for (int nt = 0; nt < 8; ++nt)
                    hp[nt * 16] = f2h(fmaxf(acc[mt][nt][r], 0.f));
            }
        }
    } else {
        float wc0[8], wc1[8];
        #pragma unroll
        for (int nt = 0; nt < 8; ++nt) {
            wc0[nt] = Wc[(nt * 16 + l15) * 2 + 0];
            wc1[nt] = Wc[(nt * 16 + l15) * 2 + 1];
        }
        float b0 = bc[0], b1 = bc[1];
        #pragma unroll
        for (int mt = 0; mt < 2; ++mt) {
            #pragma unroll
            for (int r = 0; r < 4; ++r) {
                float l0 = 0.f, l1 = 0.f;
                #pragma unroll
                for (int nt = 0; nt < 8; ++nt) {
                    float h = fmaxf(acc[mt][nt][r], 0.f);
                    l0 += h * wc0[nt];
                    l1 += h * wc1[nt];
                }
                #pragma unroll
                for (int off = 8; off > 0; off >>= 1) {
                    l0 += __shfl_down(l0, off, 16);
                    l1 += __shfl_down(l1, off, 16);
                }
                int node = rowbase + mt * 16 + quad * 4 + r;
                if (l15 == 0 && node < N_NODES) {
                    Out[(size_t)node * 2 + 0] = l0 + b0;
                    Out[(size_t)node * 2 + 1] = l1 + b1;
                }
            }
        }
    }
}

extern "C" void kernel_launch(void* const* d_in, const int* in_sizes, int n_in,
                              void* d_out, int out_size, void* d_ws, size_t ws_size,
                              hipStream_t stream)
{
    const float* x      = (const float*)d_in[0];
    const int*   ei     = (const int*)d_in[1];
    const int*   et     = (const int*)d_in[2];
    const float* Wrel1  = (const float*)d_in[3];
    const float* Wroot1 = (const float*)d_in[4];
    const float* b1     = (const float*)d_in[5];
    const float* Wrel2  = (const float*)d_in[6];
    const float* Wroot2 = (const float*)d_in[7];
    const float* b2     = (const float*)d_in[8];
    const float* Wc     = (const float*)d_in[9];
    const float* bc     = (const float*)d_in[10];
    float* out = (float*)d_out;

    char* ws = (char*)d_ws;
    size_t off = 0;
    auto alloc = [&](size_t bytes) {
        void* p = ws + off;
        off += (bytes + 255) & ~(size_t)255;
        return p;
    };
    unsigned short* xb    = (unsigned short*)alloc((size_t)PAD_N * IN_DIM * 2);
    unsigned short* h1b   = (unsigned short*)alloc((size_t)PAD_N * HID * 2);
    unsigned short* Wp    = (unsigned short*)alloc((size_t)2 * 12 * 8 * 64 * 8 * 2);
    unsigned*       rs    = (unsigned*)alloc((size_t)(M_SEG + 1) * 4);
    unsigned*       cursor= (unsigned*)alloc((size_t)M_SEG * 4);
    unsigned*       bsums = (unsigned*)alloc(256 * 4);
    unsigned*       csr   = (unsigned*)alloc((size_t)N_EDGES * 4);

    const int edge_blocks = (N_EDGES + 255) / 256;
    const int seg_blocks  = (M_SEG + 255) / 256;
    const int gemm_blocks = PAD_N / 128;                // 782
    const int prep_blocks = CVT_BLOCKS + PACK_BLOCKS + HIST_BLOCKS;

    // ---- CSR build + conversions (graph identical for both layers) ----
    hipMemsetAsync(cursor, 0, (size_t)M_SEG * 4, stream);
    prep_kernel<<<prep_blocks, 256, 0, stream>>>(
        x, xb, Wroot1, Wrel1, Wroot2, Wrel2, Wp, ei, et, cursor);
    scan1_kernel<<<SCAN_NB, 256, 0, stream>>>(cursor, rs, bsums);
    scan2_kernel<<<1, 256, 0, stream>>>(bsums);
    scan3_kernel<<<seg_blocks, 256, 0, stream>>>(rs, bsums, cursor);
    fill_kernel<<<edge_blocks, 256, 0, stream>>>(ei, et, cursor, csr);

    // ---- layer 1 (fused gather+gemm) ----
    gemm_kernel<false><<<gemm_blocks, 256, 0, stream>>>(
        xb, rs, csr, Wp, b1, h1b, nullptr, nullptr, nullptr);

    // ---- layer 2 (fused gather+gemm, FINAL classifier) ----
    gemm_kernel<true><<<gemm_blocks, 256, 0, stream>>>(
        h1b, rs, csr, Wp + (size_t)12 * 8 * 64 * 8, b2, nullptr, Wc, bc, out);
}

// Round 3
// 268.587 us; speedup vs baseline: 1.0186x; 1.0100x over previous
//
#include <hip/hip_runtime.h>
#include <hip/hip_fp16.h>

#define N_NODES 100000
#define PAD_N   100096                   // 782 * 128, padded M for GEMM tiles
#define IN_DIM 128
#define HID 128
#define N_REL 2
#define N_EDGES 500000
#define M_SEG (N_REL * N_NODES)          // 200000 (rel,node) segments
#define SCAN_BLK 1024
#define SCAN_NB ((M_SEG + SCAN_BLK - 1) / SCAN_BLK)   // 196

#define CVT_BLOCKS 12500                 // N_NODES*IN_DIM/4 / 256
#define PACK_BLOCKS 48                   // 2*12*8*64 / 256
#define HIST_BLOCKS 1954                 // ceil(N_EDGES/256)

typedef __attribute__((ext_vector_type(8))) _Float16 half8;
typedef __attribute__((ext_vector_type(4))) float float4v;

__device__ __forceinline__ unsigned short f2h(float f) {
    return __half_as_ushort(__float2half(f));   // RNE
}

// ---------------------------------------------------------------------------
// Fused prep: cvt (x fp32->fp16) | pack (weights->B-frag order, fp16) | hist.
// ---------------------------------------------------------------------------
__global__ __launch_bounds__(256) void prep_kernel(
    const float* __restrict__ X, unsigned short* __restrict__ Xb,
    const float* __restrict__ Wroot1, const float* __restrict__ Wrel1,
    const float* __restrict__ Wroot2, const float* __restrict__ Wrel2,
    unsigned short* __restrict__ Wp,
    const int* __restrict__ ei, const int* __restrict__ et,
    unsigned* __restrict__ cnt)
{
    int bid = blockIdx.x;
    if (bid < CVT_BLOCKS) {
        int i = bid * 256 + threadIdx.x;
        if (i >= N_NODES * IN_DIM / 4) return;
        float4 v = ((const float4*)X)[i];
        ushort4 o;
        o.x = f2h(v.x); o.y = f2h(v.y); o.z = f2h(v.z); o.w = f2h(v.w);
        ((ushort4*)Xb)[i] = o;
    } else if (bid < CVT_BLOCKS + PACK_BLOCKS) {
        int tid = (bid - CVT_BLOCKS) * 256 + threadIdx.x;
        int layer = tid / 6144;
        int rem   = tid % 6144;
        int ks    = rem / 512;
        int rem2  = rem % 512;
        int nt    = rem2 / 64;
        int lane  = rem2 % 64;
        int seg = ks >> 2;
        int kl  = (ks & 3) * 32 + (lane >> 4) * 8;
        int chan = nt * 16 + (lane & 15);
        const float* Wroot = layer ? Wroot2 : Wroot1;
        const float* Wrel  = layer ? Wrel2  : Wrel1;
        const float* W = (seg == 0) ? Wroot : (Wrel + (size_t)(seg - 1) * 128 * 128);
        unsigned short* dst = Wp + (size_t)tid * 8;
        #pragma unroll
        for (int j = 0; j < 8; ++j)
            dst[j] = f2h(W[(size_t)(kl + j) * 128 + chan]);
    } else {
        int e = (bid - CVT_BLOCKS - PACK_BLOCKS) * 256 + threadIdx.x;
        if (e >= N_EDGES) return;
        int dst = ei[N_EDGES + e];
        int r = et[e];
        atomicAdd(cnt + (size_t)r * N_NODES + dst, 1u);
    }
}

// ---------------------------------------------------------------------------
// Scan chain for CSR row starts
// ---------------------------------------------------------------------------
__global__ __launch_bounds__(256) void scan1_kernel(
    const unsigned* __restrict__ cnt,
    unsigned* __restrict__ rs, unsigned* __restrict__ bsums)
{
    __shared__ unsigned sdata[256];
    int t = threadIdx.x;
    int base = blockIdx.x * SCAN_BLK + t * 4;
    unsigned v[4]; unsigned s = 0;
    #pragma unroll
    for (int j = 0; j < 4; ++j) {
        v[j] = (base + j < M_SEG) ? cnt[base + j] : 0u;
        s += v[j];
    }
    sdata[t] = s;
    __syncthreads();
    #pragma unroll
    for (int off = 1; off < 256; off <<= 1) {
        unsigned x = (t >= off) ? sdata[t - off] : 0u;
        __syncthreads();
        if (t >= off) sdata[t] += x;
        __syncthreads();
    }
    unsigned excl = (t > 0) ? sdata[t - 1] : 0u;
    if (t == 255) bsums[blockIdx.x] = sdata[255];
    unsigned run = excl;
    #pragma unroll
    for (int j = 0; j < 4; ++j) {
        if (base + j < M_SEG) rs[base + j] = run;
        run += v[j];
    }
}

__global__ __launch_bounds__(256) void scan2_kernel(unsigned* __restrict__ bsums)
{
    __shared__ unsigned sdata[256];
    int t = threadIdx.x;
    sdata[t] = (t < SCAN_NB) ? bsums[t] : 0u;
    __syncthreads();
    #pragma unroll
    for (int off = 1; off < 256; off <<= 1) {
        unsigned x = (t >= off) ? sdata[t - off] : 0u;
        __syncthreads();
        if (t >= off) sdata[t] += x;
        __syncthreads();
    }
    if (t < SCAN_NB) bsums[t] = (t > 0) ? sdata[t - 1] : 0u;
}

__global__ __launch_bounds__(256) void scan3_kernel(
    unsigned* __restrict__ rs, const unsigned* __restrict__ bsums,
    unsigned* __restrict__ cursor)
{
    int i = blockIdx.x * blockDim.x + threadIdx.x;
    if (i < M_SEG) {
        unsigned v = rs[i] + bsums[i >> 10];
        rs[i] = v;
        cursor[i] = v;
    }
    if (i == 0) rs[M_SEG] = N_EDGES;
}

__global__ __launch_bounds__(256) void fill_kernel(
    const int* __restrict__ ei, const int* __restrict__ et,
    unsigned* __restrict__ cursor, unsigned* __restrict__ csr)
{
    int e = blockIdx.x * blockDim.x + threadIdx.x;
    if (e >= N_EDGES) return;
    int src = ei[e];
    int dst = ei[N_EDGES + e];
    int r = et[e];
    unsigned pos = atomicAdd(cursor + (size_t)r * N_NODES + dst, 1u);
    csr[pos] = (unsigned)src;
}

// ---------------------------------------------------------------------------
// Fused gather + MFMA GEMM (fp16), occupancy-optimized:
//  * wave owns 16 rows (no mt dim): acc 64->32, gather walks 4->2, a2 64->32
//    regs.  Peak unified regs ~150 -> 3 waves/SIMD resident (was ~190 -> 2).
//  * grid 2x: 1564 blocks of 64 rows -> more schedulable units per CU.
//  * gather processes 2 edge-slots per relation walk per iteration (8 edges,
//    16x16B row loads in flight) -> serial trips ~5 instead of ~10.
//  * CSR IDs software-pipelined: next iteration's 4 ID loads issue alongside
//    the current row loads, so per-iter chain = one row-load latency.
//  * No LDS, no __syncthreads: B read from L2 with depth-2 register
//    ping-pong (all indices compile-time).
// ---------------------------------------------------------------------------
template <bool FINAL>
__global__ __launch_bounds__(256) void gemm_kernel(
    const unsigned short* __restrict__ Xin,   // [PAD_N][128] fp16 (layer input + gather source)
    const unsigned* __restrict__ rs,          // [M_SEG+1] CSR row starts
    const unsigned* __restrict__ csr,         // [N_EDGES] src node per slot
    const unsigned short* __restrict__ Wp,    // packed [12][8][64][8] fp16
    const float* __restrict__ bias,           // [128] fp32
    unsigned short* __restrict__ Hout,        // [PAD_N][128] fp16 (!FINAL)
    const float* __restrict__ Wc,             // [128][2] fp32 (FINAL)
    const float* __restrict__ bc,             // [2] fp32 (FINAL)
    float* __restrict__ Out)                  // [N][2] fp32 (FINAL)
{
    const int t    = threadIdx.x;
    const int w    = t >> 6;          // wave 0..3
    const int lane = t & 63;
    const int l15  = lane & 15;
    const int quad = lane >> 4;
    const int rowbase = blockIdx.x * 64 + w * 16;   // this wave's 16 nodes
    const int koff = quad * 8;

    const uint4* __restrict__ X4 = (const uint4*)Xin;   // 16B units

    // ---- segment bounds for the 2 relation walks of this lane's node ----
    const int node = rowbase + l15;
    unsigned p_[2], e_[2]; float inv_[2];
    #pragma unroll
    for (int r = 0; r < 2; ++r) {
        unsigned st = 0, en = 0;
        if (node < N_NODES) {
            unsigned sg = (unsigned)r * N_NODES + (unsigned)node;
            st = rs[sg];
            en = rs[sg + 1];
        }
        p_[r] = st; e_[r] = en;
        unsigned d = en - st;
        inv_[r] = 1.0f / (float)(d ? d : 1u);
    }

    __half2 a2[2][4][4];              // [r][ksl][j] — statically indexed
    #pragma unroll
    for (int r = 0; r < 2; ++r)
        #pragma unroll
        for (int ksl = 0; ksl < 4; ++ksl)
            #pragma unroll
            for (int j = 0; j < 4; ++j)
                a2[r][ksl][j] = __float2half2_rn(0.f);

    const __half2 one2  = __float2half2_rn(1.f);
    const __half2 zero2 = __float2half2_rn(0.f);

    // prolog: IDs for the first 2 edge-slots of each walk
    unsigned id[2][2];
    #pragma unroll
    for (int r = 0; r < 2; ++r)
        #pragma unroll
        for (int s = 0; s < 2; ++s) {
            unsigned q = p_[r] + (unsigned)s;
            id[r][s] = csr[q < e_[r] ? q : 0u];
        }

    while (__any((p_[0] < e_[0]) | (p_[1] < e_[1]))) {
        // activity of the current 4 edge-slots (from p_, no loads)
        bool act[2][2];
        #pragma unroll
        for (int r = 0; r < 2; ++r)
            #pragma unroll
            for (int s = 0; s < 2; ++s)
                act[r][s] = (p_[r] + (unsigned)s) < e_[r];

        // 16 independent 16B row loads for the current IDs
        uint4 v[2][2][4];
        #pragma unroll
        for (int r = 0; r < 2; ++r)
            #pragma unroll
            for (int s = 0; s < 2; ++s) {
                const uint4* row = X4 +
                    ((size_t)(act[r][s] ? id[r][s] : 0u) << 4) + quad;
                v[r][s][0] = row[0];
                v[r][s][1] = row[4];
                v[r][s][2] = row[8];
                v[r][s][3] = row[12];
            }

        // advance pointers and prefetch NEXT iteration's IDs (independent of v)
        unsigned pn[2];
        #pragma unroll
        for (int r = 0; r < 2; ++r) {
            unsigned q = p_[r] + 2u;
            pn[r] = q > e_[r] ? e_[r] : q;
        }
        unsigned idn[2][2];
        #pragma unroll
        for (int r = 0; r < 2; ++r)
            #pragma unroll
            for (int s = 0; s < 2; ++s) {
                unsigned q = pn[r] + (unsigned)s;
                idn[r][s] = csr[q < e_[r] ? q : 0u];
            }

        // predicated packed-fma accumulate (slot order preserves edge order)
        #pragma unroll
        for (int r = 0; r < 2; ++r)
            #pragma unroll
            for (int s = 0; s < 2; ++s) {
                __half2 m = act[r][s] ? one2 : zero2;
                #pragma unroll
                for (int ksl = 0; ksl < 4; ++ksl)
                    #pragma unroll
                    for (int j = 0; j < 4; ++j)
                        a2[r][ksl][j] = __hfma2(((const __half2*)&v[r][s][ksl])[j],
                                                m, a2[r][ksl][j]);
            }

        #pragma unroll
        for (int r = 0; r < 2; ++r) {
            p_[r] = pn[r];
            #pragma unroll
            for (int s = 0; s < 2; ++s) id[r][s] = idn[r][s];
        }
    }

    // scale to means
    half8 ag[2][4];                   // [r][ksl]
    #pragma unroll
    for (int r = 0; r < 2; ++r) {
        __half2 s2 = __float2half2_rn(inv_[r]);
        #pragma unroll
        for (int ksl = 0; ksl < 4; ++ksl) {
            half8 h;
            #pragma unroll
            for (int j = 0; j < 4; ++j)
                ((__half2*)&h)[j] = __hmul2(a2[r][ksl][j], s2);
            ag[r][ksl] = h;
        }
    }

    // ---- MFMA phase: B (and seg-0 A) direct-from-global, depth-2 prefetch ----
    auto ldB = [&](int ks, int nt) -> half8 {
        return *(const half8*)(Wp + ((size_t)(ks * 8 + nt) * 64 + lane) * 8);
    };
    const unsigned short* aBase = Xin + (size_t)(rowbase + l15) * 128 + koff;
    auto ldA = [&](int ks) -> half8 {
        return *(const half8*)(aBase + (ks & 3) * 32);
    };

    float4v acc[8];
    #pragma unroll
    for (int nt = 0; nt < 8; ++nt) {
        float bv = bias[nt * 16 + l15];
        acc[nt] = float4v{bv, bv, bv, bv};
    }

    half8 bb[2][8];                   // ping-pong, ks&1 is compile-time
    half8 ax[2];
    #pragma unroll
    for (int nt = 0; nt < 8; ++nt) bb[0][nt] = ldB(0, nt);
    ax[0] = ldA(0);

    #pragma unroll
    for (int ks = 0; ks < 12; ++ks) {
        if (ks + 1 < 12) {
            #pragma unroll
            for (int nt = 0; nt < 8; ++nt)
                bb[(ks + 1) & 1][nt] = ldB(ks + 1, nt);
            if (ks + 1 < 4) ax[(ks + 1) & 1] = ldA(ks + 1);
        }
        half8 A = (ks < 4) ? ax[ks & 1] : ag[(ks >> 2) - 1][ks & 3];
        #pragma unroll
        for (int nt = 0; nt < 8; ++nt)
            acc[nt] = __builtin_amdgcn_mfma_f32_16x16x32_f16(A, bb[ks & 1][nt], acc[nt], 0, 0, 0);
    }

    if (!FINAL) {
        // D layout: row = quad*4 + rr, col = l15 (within each 16x16 tile)
        #pragma unroll
        for (int rr = 0; rr < 4; ++rr) {
            int n2 = rowbase + quad * 4 + rr;
            unsigned short* hp = Hout + (size_t)n2 * 128 + l15;
            #pragma unroll
            for (int nt = 0; nt < 8; ++nt)
                hp[nt * 16] = f2h(fmaxf(acc[nt][rr], 0.f));
        }
    } else {
        float wc0[8], wc1[8];
        #pragma unroll
        for (int nt = 0; nt < 8; ++nt) {
            wc0[nt] = Wc[(nt * 16 + l15) * 2 + 0];
            wc1[nt] = Wc[(nt * 16 + l15) * 2 + 1];
        }
        float b0 = bc[0], b1 = bc[1];
        #pragma unroll
        for (int rr = 0; rr < 4; ++rr) {
            float l0 = 0.f, l1 = 0.f;
            #pragma unroll
            for (int nt = 0; nt < 8; ++nt) {
                float h = fmaxf(acc[nt][rr], 0.f);
                l0 += h * wc0[nt];
                l1 += h * wc1[nt];
            }
            #pragma unroll
            for (int off = 8; off > 0; off >>= 1) {
                l0 += __shfl_down(l0, off, 16);
                l1 += __shfl_down(l1, off, 16);
            }
            int n2 = rowbase + quad * 4 + rr;
            if (l15 == 0 && n2 < N_NODES) {
                Out[(size_t)n2 * 2 + 0] = l0 + b0;
                Out[(size_t)n2 * 2 + 1] = l1 + b1;
            }
        }
    }
}

extern "C" void kernel_launch(void* const* d_in, const int* in_sizes, int n_in,
                              void* d_out, int out_size, void* d_ws, size_t ws_size,
                              hipStream_t stream)
{
    const float* x      = (const float*)d_in[0];
    const int*   ei     = (const int*)d_in[1];
    const int*   et     = (const int*)d_in[2];
    const float* Wrel1  = (const float*)d_in[3];
    const float* Wroot1 = (const float*)d_in[4];
    const float* b1     = (const float*)d_in[5];
    const float* Wrel2  = (const float*)d_in[6];
    const float* Wroot2 = (const float*)d_in[7];
    const float* b2     = (const float*)d_in[8];
    const float* Wc     = (const float*)d_in[9];
    const float* bc     = (const float*)d_in[10];
    float* out = (float*)d_out;

    char* ws = (char*)d_ws;
    size_t off = 0;
    auto alloc = [&](size_t bytes) {
        void* p = ws + off;
        off += (bytes + 255) & ~(size_t)255;
        return p;
    };
    unsigned short* xb    = (unsigned short*)alloc((size_t)PAD_N * IN_DIM * 2);
    unsigned short* h1b   = (unsigned short*)alloc((size_t)PAD_N * HID * 2);
    unsigned short* Wp    = (unsigned short*)alloc((size_t)2 * 12 * 8 * 64 * 8 * 2);
    unsigned*       rs    = (unsigned*)alloc((size_t)(M_SEG + 1) * 4);
    unsigned*       cursor= (unsigned*)alloc((size_t)M_SEG * 4);
    unsigned*       bsums = (unsigned*)alloc(256 * 4);
    unsigned*       csr   = (unsigned*)alloc((size_t)N_EDGES * 4);

    const int edge_blocks = (N_EDGES + 255) / 256;
    const int seg_blocks  = (M_SEG + 255) / 256;
    const int gemm_blocks = PAD_N / 64;                 // 1564
    const int prep_blocks = CVT_BLOCKS + PACK_BLOCKS + HIST_BLOCKS;

    // ---- CSR build + conversions (graph identical for both layers) ----
    hipMemsetAsync(cursor, 0, (size_t)M_SEG * 4, stream);
    prep_kernel<<<prep_blocks, 256, 0, stream>>>(
        x, xb, Wroot1, Wrel1, Wroot2, Wrel2, Wp, ei, et, cursor);
    scan1_kernel<<<SCAN_NB, 256, 0, stream>>>(cursor, rs, bsums);
    scan2_kernel<<<1, 256, 0, stream>>>(bsums);
    scan3_kernel<<<seg_blocks, 256, 0, stream>>>(rs, bsums, cursor);
    fill_kernel<<<edge_blocks, 256, 0, stream>>>(ei, et, cursor, csr);

    // ---- layer 1 (fused gather+gemm) ----
    gemm_kernel<false><<<gemm_blocks, 256, 0, stream>>>(
        xb, rs, csr, Wp, b1, h1b, nullptr, nullptr, nullptr);

    // ---- layer 2 (fused gather+gemm, FINAL classifier) ----
    gemm_kernel<true><<<gemm_blocks, 256, 0, stream>>>(
        h1b, rs, csr, Wp + (size_t)12 * 8 * 64 * 8, b2, nullptr, Wc, bc, out);
}